// Round 2
// baseline (395.494 us; speedup 1.0000x reference)
//
#include <hip/hip_runtime.h>

#define H 128
#define NPB 256       // nodes per scan block

// fp32 -> bf16 round-to-nearest-even
static __device__ __forceinline__ unsigned short f2bf(float f) {
  unsigned u = __float_as_uint(f);
  u += 0x7FFFu + ((u >> 16) & 1u);
  return (unsigned short)(u >> 16);
}

// ---------------------------------------------------------------------------
// GEMM: X0 = notes @ w, register-blocked (R4-proven, verbatim).
// x0 stored bf16; rows >= garment written fp32 to output tail.
// ---------------------------------------------------------------------------
__global__ __launch_bounds__(256) void gemm_kernel(
    const float* __restrict__ notes, const float* __restrict__ w,
    const int* __restrict__ g_ptr, unsigned short* __restrict__ x0h,
    float* __restrict__ out, int n_nodes) {
  __shared__ float wtile[32 * H];   // 16 KB
  __shared__ float ntile[64 * 32];  // 8 KB
  const int tid = threadIdx.x;
  const int tx = tid & 31;
  const int ty = tid >> 5;
  const int rowBlk = blockIdx.x * 64;
  const int g = *g_ptr;

  float acc[8][4];
#pragma unroll
  for (int i = 0; i < 8; ++i)
#pragma unroll
    for (int j = 0; j < 4; ++j) acc[i][j] = 0.f;

  for (int kc = 0; kc < H; kc += 32) {
    __syncthreads();
    {
      const float4* wg = (const float4*)(w + (size_t)kc * H);
      float4* wl = (float4*)wtile;
#pragma unroll
      for (int i = 0; i < 4; ++i) wl[tid + i * 256] = wg[tid + i * 256];
    }
    {
      float4* nl = (float4*)ntile;
#pragma unroll
      for (int i = 0; i < 2; ++i) {
        const int idx = tid + i * 256;
        const int row = idx >> 3;
        const int q = idx & 7;
        const int rr = min(rowBlk + row, n_nodes - 1);
        nl[idx] = *(const float4*)(notes + (size_t)rr * H + kc + q * 4);
      }
    }
    __syncthreads();
#pragma unroll 8
    for (int kk = 0; kk < 32; ++kk) {
      const float4 b4 = *(const float4*)&wtile[kk * H + tx * 4];
      float a[8];
#pragma unroll
      for (int i = 0; i < 8; ++i) a[i] = ntile[(ty * 8 + i) * 32 + kk];
#pragma unroll
      for (int i = 0; i < 8; ++i) {
        acc[i][0] += a[i] * b4.x;
        acc[i][1] += a[i] * b4.y;
        acc[i][2] += a[i] * b4.z;
        acc[i][3] += a[i] * b4.w;
      }
    }
  }

#pragma unroll
  for (int i = 0; i < 8; ++i) {
    const int r = rowBlk + ty * 8 + i;
    if (r < n_nodes) {
      ushort4 h;
      h.x = f2bf(acc[i][0]);
      h.y = f2bf(acc[i][1]);
      h.z = f2bf(acc[i][2]);
      h.w = f2bf(acc[i][3]);
      *(ushort4*)(x0h + (size_t)r * H + tx * 4) = h;
      if (r >= g) {
        float4 v;
        v.x = acc[i][0]; v.y = acc[i][1]; v.z = acc[i][2]; v.w = acc[i][3];
        *(float4*)(out + (size_t)(n_nodes + r - g) * H + tx * 4) = v;
      }
    }
  }
}

// ---------------------------------------------------------------------------
// Degree count: one global atomic per edge into per-node counters.
// 1.6M atomics over 400 KB (L2-resident) -> memory-side atomic fast path.
// ---------------------------------------------------------------------------
__global__ __launch_bounds__(256) void deg_count_kernel(
    const int* __restrict__ esrc, int* __restrict__ deg, int n_edges) {
  const int i = blockIdx.x * 256 + threadIdx.x;
  if (i >= n_edges) return;
  atomicAdd(&deg[esrc[i]], 1);
}

// ---------------------------------------------------------------------------
// Per-bucket (256-node) degree sums. No atomics; plain LDS tree reduction.
// ---------------------------------------------------------------------------
__global__ __launch_bounds__(256) void bucket_sum_kernel(
    const int* __restrict__ deg, int* __restrict__ bucketCount, int n_nodes) {
  __shared__ int red[256];
  const int t = threadIdx.x;
  const int node = blockIdx.x * 256 + t;
  red[t] = (node < n_nodes) ? deg[node] : 0;
  __syncthreads();
  for (int o = 128; o > 0; o >>= 1) {
    if (t < o) red[t] += red[t + o];
    __syncthreads();
  }
  if (t == 0) bucketCount[blockIdx.x] = red[0];
}

// ---------------------------------------------------------------------------
// Bucket scan: single block; exclusive prefix over bucketCount -> bucketBase.
// Also writes off[n_nodes] = n_edges.
// ---------------------------------------------------------------------------
__global__ __launch_bounds__(256) void bucket_scan_kernel(
    const int* __restrict__ bucketCount, int* __restrict__ bucketBase,
    int* __restrict__ off, int nb, int n_nodes, int n_edges) {
  __shared__ int part[256];
  const int t = threadIdx.x;
  const int K = (nb + 255) / 256;
  const int lo = t * K;
  const int hi = min(lo + K, nb);
  int sum = 0;
  for (int i = lo; i < hi; ++i) sum += bucketCount[i];
  part[t] = sum;
  __syncthreads();
  for (int o = 1; o < 256; o <<= 1) {
    const int tv = (t >= o) ? part[t - o] : 0;
    __syncthreads();
    part[t] += tv;
    __syncthreads();
  }
  int run = (t == 0) ? 0 : part[t - 1];
  for (int i = lo; i < hi; ++i) {
    bucketBase[i] = run;
    run += bucketCount[i];
  }
  if (t == 255) {
    bucketBase[nb] = part[255];
    off[n_nodes] = n_edges;
  }
}

// ---------------------------------------------------------------------------
// Node offsets: per-bucket LDS exclusive scan of degrees + bucketBase
// -> off[node] and cursor[node].
// ---------------------------------------------------------------------------
__global__ __launch_bounds__(256) void node_off_kernel(
    const int* __restrict__ deg, const int* __restrict__ bucketBase,
    int* __restrict__ off, int* __restrict__ cursor, int n_nodes) {
  __shared__ int sc[256];
  const int t = threadIdx.x;
  const int node = blockIdx.x * 256 + t;
  const int v = (node < n_nodes) ? deg[node] : 0;
  sc[t] = v;
  __syncthreads();
  for (int o = 1; o < 256; o <<= 1) {
    const int tv = (t >= o) ? sc[t - o] : 0;
    __syncthreads();
    sc[t] += tv;
    __syncthreads();
  }
  if (node < n_nodes) {
    const int o0 = bucketBase[blockIdx.x] + sc[t] - v;  // exclusive
    off[node] = o0;
    cursor[node] = o0;
  }
}

// ---------------------------------------------------------------------------
// Direct fill: one pass; atomic per-node cursor gives final slot.
// Replaces the old fill+sort double-stage entirely.
// ---------------------------------------------------------------------------
__global__ __launch_bounds__(256) void direct_fill_kernel(
    const int* __restrict__ esrc, const int* __restrict__ edst,
    const float* __restrict__ ew, int* __restrict__ cursor,
    int2* __restrict__ sedge2, int n_edges) {
  const int i = blockIdx.x * 256 + threadIdx.x;
  if (i >= n_edges) return;
  const int s = esrc[i];
  const int slot = atomicAdd(&cursor[s], 1);
  int2 pk;
  pk.x = edst[i];
  pk.y = __float_as_int(ew[i]);
  sedge2[slot] = pk;
}

// ---------------------------------------------------------------------------
// Gather v2: one wave per node. Edge metadata loaded COALESCED (lane-indexed,
// one vector load per <=64 edges) then broadcast via __shfl (uniform index).
// 8 independent row loads in flight per group -> breaks the serial
// sedge->row dependent-load chain that made v1 latency-bound.
// ---------------------------------------------------------------------------
__global__ __launch_bounds__(256) void gather_kernel(
    const int* __restrict__ off, const int2* __restrict__ sedge,
    const unsigned short* __restrict__ x0h, const float* __restrict__ b,
    float* __restrict__ out, int n_nodes) {
  const int wave = blockIdx.x * (blockDim.x >> 6) + (threadIdx.x >> 6);
  const int lane = threadIdx.x & 63;
  if (wave >= n_nodes) return;
  const int beg = off[wave];
  const int end = off[wave + 1];
  const int deg = end - beg;
  const unsigned* __restrict__ x0u = (const unsigned*)x0h;

  float2 acc[8];
#pragma unroll
  for (int j = 0; j < 8; ++j) acc[j] = make_float2(0.f, 0.f);

  for (int base = 0; base < deg; base += 64) {
    const int m = min(64, deg - base);
    // Coalesced metadata load; clamp keeps all lanes in-bounds & convergent.
    const int2 md = sedge[beg + base + min(lane, m - 1)];
    const float mw = __int_as_float(md.y);
    for (int e = 0; e < m; e += 8) {
      int d[8];
      float wv[8];
#pragma unroll
      for (int j = 0; j < 8; ++j) {
        const int idx = e + j;
        const int src = min(idx, m - 1);     // uniform
        d[j] = __shfl(md.x, src);
        const float wj = __shfl(mw, src);
        wv[j] = (idx < m) ? wj : 0.f;        // zero-weight padding, no branch
      }
      unsigned u[8];
#pragma unroll
      for (int j = 0; j < 8; ++j) u[j] = x0u[(size_t)d[j] * 64 + lane];
#pragma unroll
      for (int j = 0; j < 8; ++j) {
        acc[j].x += __uint_as_float(u[j] << 16) * wv[j];
        acc[j].y += __uint_as_float(u[j] & 0xFFFF0000u) * wv[j];
      }
    }
  }

  const float2 bb = ((const float2*)b)[lane];
  float2 r;
  r.x = fmaxf(acc[0].x + acc[1].x + acc[2].x + acc[3].x + acc[4].x + acc[5].x +
                  acc[6].x + acc[7].x + bb.x,
              0.f);
  r.y = fmaxf(acc[0].y + acc[1].y + acc[2].y + acc[3].y + acc[4].y + acc[5].y +
                  acc[6].y + acc[7].y + bb.y,
              0.f);
  ((float2*)out)[(size_t)wave * 64 + lane] = r;
}

// ---------------------------------------------------------------------------
// Fallback path (constraints violated): atomic scatter + epilogue.
// ---------------------------------------------------------------------------
__global__ __launch_bounds__(256) void scatter_kernel(
    const int* __restrict__ esrc, const int* __restrict__ edst,
    const float* __restrict__ ew, const unsigned short* __restrict__ x0h,
    float* __restrict__ acc, int n_edges) {
  const int lane = threadIdx.x & 63;
  const int waveId = blockIdx.x * (blockDim.x >> 6) + (threadIdx.x >> 6);
  const int nWaves = gridDim.x * (blockDim.x >> 6);
  const unsigned* __restrict__ x0u = (const unsigned*)x0h;
  for (int e = waveId; e < n_edges; e += nWaves) {
    const int s = esrc[e];
    const int d = edst[e];
    const float wt = ew[e];
    const unsigned u = x0u[(size_t)d * 64 + lane];
    float* p = acc + (size_t)s * H + lane * 2;
    atomicAdd(p, __uint_as_float(u << 16) * wt);
    atomicAdd(p + 1, __uint_as_float(u & 0xFFFF0000u) * wt);
  }
}

__global__ __launch_bounds__(256) void epilogue_kernel(
    float* __restrict__ out, const float* __restrict__ b, int n4) {
  const int i = blockIdx.x * blockDim.x + threadIdx.x;
  if (i >= n4) return;
  float4* o4 = (float4*)out;
  const float4* b4 = (const float4*)b;
  float4 v = o4[i];
  const float4 bb = b4[i & 31];
  v.x = fmaxf(v.x + bb.x, 0.f);
  v.y = fmaxf(v.y + bb.y, 0.f);
  v.z = fmaxf(v.z + bb.z, 0.f);
  v.w = fmaxf(v.w + bb.w, 0.f);
  o4[i] = v;
}

extern "C" void kernel_launch(void* const* d_in, const int* in_sizes, int n_in,
                              void* d_out, int out_size, void* d_ws, size_t ws_size,
                              hipStream_t stream) {
  const float* notes = (const float*)d_in[0];
  const float* w     = (const float*)d_in[1];
  const float* b     = (const float*)d_in[2];
  const int*   esrc  = (const int*)d_in[3];
  const int*   edst  = (const int*)d_in[4];
  const float* ew    = (const float*)d_in[5];
  const int*   gptr  = (const int*)d_in[6];

  const int n_nodes = in_sizes[0] / H;
  const int n_edges = in_sizes[3];
  float* out = (float*)d_out;

  const int nb = (n_nodes + NPB - 1) / NPB;

  // Workspace carve-up (256B-aligned regions).
  char* ws = (char*)d_ws;
  size_t p = 0;
  auto alloc = [&](size_t bytes) -> char* {
    char* cur = ws + p;
    p = (p + bytes + 255) & ~(size_t)255;
    return cur;
  };
  unsigned short* x0h = (unsigned short*)alloc((size_t)n_nodes * H * 2);
  int*  deg          = (int*)alloc((size_t)n_nodes * sizeof(int));
  int*  cursor       = (int*)alloc((size_t)n_nodes * sizeof(int));
  int*  off          = (int*)alloc(((size_t)n_nodes + 1) * sizeof(int));
  int*  bucketCount  = (int*)alloc((size_t)nb * sizeof(int));
  int*  bucketBase   = (int*)alloc(((size_t)nb + 1) * sizeof(int));
  int2* sedge2       = (int2*)alloc((size_t)n_edges * sizeof(int2));
  const bool ok = (p <= ws_size);

  // GEMM (also writes concat tail rows fp32; x0 stored bf16).
  gemm_kernel<<<(n_nodes + 63) / 64, 256, 0, stream>>>(notes, w, gptr, x0h, out,
                                                       n_nodes);

  if (ok) {
    const int eblocks = (n_edges + 255) / 256;
    hipMemsetAsync(deg, 0, (size_t)n_nodes * sizeof(int), stream);
    deg_count_kernel<<<eblocks, 256, 0, stream>>>(esrc, deg, n_edges);
    bucket_sum_kernel<<<nb, 256, 0, stream>>>(deg, bucketCount, n_nodes);
    bucket_scan_kernel<<<1, 256, 0, stream>>>(bucketCount, bucketBase, off, nb,
                                              n_nodes, n_edges);
    node_off_kernel<<<nb, 256, 0, stream>>>(deg, bucketBase, off, cursor,
                                            n_nodes);
    direct_fill_kernel<<<eblocks, 256, 0, stream>>>(esrc, edst, ew, cursor,
                                                    sedge2, n_edges);
    gather_kernel<<<(n_nodes + 3) / 4, 256, 0, stream>>>(off, sedge2, x0h, b,
                                                         out, n_nodes);
  } else {
    hipMemsetAsync(d_out, 0, (size_t)n_nodes * H * sizeof(float), stream);
    scatter_kernel<<<2048, 256, 0, stream>>>(esrc, edst, ew, x0h, out, n_edges);
    const int n4 = n_nodes * H / 4;
    epilogue_kernel<<<(n4 + 255) / 256, 256, 0, stream>>>(out, b, n4);
  }
}